// Round 3
// baseline (25.595 us; speedup 1.0000x reference)
//
#include <hip/hip_runtime.h>
#include <hip/hip_bf16.h>

// Problem: B=32, T=1024, D=512, x float32 (B,T,D) viewed flat as per-batch
// row-major M[D][T].  Row 0 = padding, rows 1..D-1 = signal.
//   norm[t]      = sum_{d=1..D-1} |M[d][t]|
//   one_minus[t] = 1 / (1 + exp(M[0][t] - norm[t]))
//   out[0][t]    = M[0][t] * (1 + |padding_amount|)
//   out[d][t]    = M[d][t] * one_minus[t]                 (d >= 1)
//
// R3: barrier-desynchronization probe.  Same single-HBM-pass register-cache
// scheme as R2 (16 x float4 per thread), but 4 independent blocks per CU:
//   block = 256 threads (4 waves), tile = 512 rows x 32 cols, grid = 1024.
// When one block is in its reduce/__syncthreads window, 3 other blocks on
// the CU keep the memory pipes busy.  Reads are 128 B contiguous per
// row-group (still full cache lines).

#define BB 32
#define TT 1024
#define DD 512

constexpr int TB    = 32;             // columns per block tile
constexpr int WAVES = 4;              // waves per block
constexpr int RPW   = DD / WAVES;     // 128 rows per wave
constexpr int R     = 16;             // rows (float4 loads) per thread
// per wave: 8 col-groups (lane&7) x 8 row-groups (lane>>3) x 16 rows = 128 rows

__global__ __launch_bounds__(256, 4) void padding_bottleneck_kernel(
    const float* __restrict__ x,
    const float* __restrict__ padding_amount,
    float* __restrict__ out)
{
    const int blk  = blockIdx.x;            // 0..1023
    const int b    = blk >> 5;              // batch (32)
    const int tile = blk & 31;              // 32 column-tiles per batch
    const int lane = threadIdx.x & 63;
    const int wav  = threadIdx.x >> 6;      // 0..3
    const int cg   = lane & 7;              // column group (4 cols each)
    const int rg   = lane >> 3;             // row group 0..7
    const int c0   = cg * 4;                // col within tile
    const int t0   = tile * TB + c0;        // global col
    const int r0   = wav * RPW + rg * R;    // first row owned by this thread

    const size_t base = (size_t)b * DD * TT + (size_t)r0 * TT + t0;
    const float* src = x + base;
    float*       dst = out + base;

    // ---- pass 1: load 16 float4 into registers, per-column |.| partials
    float4 v[R];
    float s0 = 0.f, s1 = 0.f, s2 = 0.f, s3 = 0.f;
#pragma unroll
    for (int j = 0; j < R; ++j) {
        v[j] = *reinterpret_cast<const float4*>(src + (size_t)j * TT);
        s0 += fabsf(v[j].x); s1 += fabsf(v[j].y);
        s2 += fabsf(v[j].z); s3 += fabsf(v[j].w);
    }

    __shared__ float psum[WAVES][TB];
    __shared__ float padv[TB];

    const bool has_pad = (wav == 0 && rg == 0);   // this thread's j==0 is row d=0
    if (has_pad) {
        s0 -= fabsf(v[0].x); s1 -= fabsf(v[0].y);
        s2 -= fabsf(v[0].z); s3 -= fabsf(v[0].w);
        *reinterpret_cast<float4*>(&padv[c0]) = v[0];
    }

    // ---- fold the 8 row-groups of this wave (lanes ^8, ^16, ^32)
    s0 += __shfl_xor(s0, 8);  s1 += __shfl_xor(s1, 8);
    s2 += __shfl_xor(s2, 8);  s3 += __shfl_xor(s3, 8);
    s0 += __shfl_xor(s0, 16); s1 += __shfl_xor(s1, 16);
    s2 += __shfl_xor(s2, 16); s3 += __shfl_xor(s3, 16);
    s0 += __shfl_xor(s0, 32); s1 += __shfl_xor(s1, 32);
    s2 += __shfl_xor(s2, 32); s3 += __shfl_xor(s3, 32);

    if (rg == 0) {
        float4 t = make_float4(s0, s1, s2, s3);
        *reinterpret_cast<float4*>(&psum[wav][c0]) = t;
    }
    __syncthreads();

    // ---- per-column weight (redundantly per thread for its 4 columns)
    float n0 = 0.f, n1 = 0.f, n2 = 0.f, n3 = 0.f;
#pragma unroll
    for (int s = 0; s < WAVES; ++s) {
        float4 p = *reinterpret_cast<const float4*>(&psum[s][c0]);
        n0 += p.x; n1 += p.y; n2 += p.z; n3 += p.w;
    }
    const float4 pv = *reinterpret_cast<const float4*>(&padv[c0]);
    const float om0 = 1.f / (1.f + __expf(pv.x - n0));
    const float om1 = 1.f / (1.f + __expf(pv.y - n1));
    const float om2 = 1.f / (1.f + __expf(pv.z - n2));
    const float om3 = 1.f / (1.f + __expf(pv.w - n3));
    const float scale = 1.f + fabsf(padding_amount[0]);

    // ---- pass 2: scale cached registers, store float4
#pragma unroll
    for (int j = 0; j < R; ++j) {
        float4 o;
        if (has_pad && j == 0) {
            o.x = v[0].x * scale; o.y = v[0].y * scale;
            o.z = v[0].z * scale; o.w = v[0].w * scale;
        } else {
            o.x = v[j].x * om0; o.y = v[j].y * om1;
            o.z = v[j].z * om2; o.w = v[j].w * om3;
        }
        *reinterpret_cast<float4*>(dst + (size_t)j * TT) = o;
    }
}

extern "C" void kernel_launch(void* const* d_in, const int* in_sizes, int n_in,
                              void* d_out, int out_size, void* d_ws, size_t ws_size,
                              hipStream_t stream)
{
    const float* x  = (const float*)d_in[0];
    const float* pa = (const float*)d_in[1];
    float* out      = (float*)d_out;

    // one block per (batch, 32-col tile): 32 * 32 = 1024 blocks = 4 per CU
    dim3 grid(BB * (TT / TB));
    dim3 block(WAVES * 64);
    padding_bottleneck_kernel<<<grid, block, 0, stream>>>(x, pa, out);
}